// Round 1
// baseline (9968.838 us; speedup 1.0000x reference)
//
#include <hip/hip_runtime.h>
#include <math.h>

#define NB 8
#define NV 64
#define NM 1024
#define NR 3
#define NT 16
#define KR 8
#define RTOT 48                 // NR*NT
#define RADIUSF 40.0f
#define TWO_PIF 6.283185307179586f

// ---------------------------------------------------------------------------
// Pair geometry: replicates the reference bilinear polar binning exactly.
// ---------------------------------------------------------------------------
__device__ __forceinline__ void pair_geom(float relx, float rely, float mask,
                                          float& valid, float& win,
                                          int bin[4], float cw[4]) {
    float d = sqrtf(relx * relx + rely * rely + 1e-12f);
    valid = (d < RADIUSF) ? mask : 0.0f;
    float q = d * (1.0f / RADIUSF);
    float w1 = fmaxf(1.0f - q * q, 0.0f);
    win = w1 * w1 * w1;
    float u = fminf(fmaxf(q, 0.0f), 1.0f) * (float)(NR - 1);
    float r0f = floorf(u);
    float wr = u - r0f;
    int r0 = (int)r0f;
    int r1 = min(r0 + 1, NR - 1);
    float a = atan2f(rely, relx) * (1.0f / TWO_PIF);
    a = a - floorf(a);                  // mod 1 -> [0,1]
    float t = a * (float)NT;
    float t0f = floorf(t);
    float wt = t - t0f;
    int t0 = ((int)t0f) & (NT - 1);
    int t1 = (t0 + 1) & (NT - 1);
    bin[0] = r0 * NT + t0; cw[0] = (1.0f - wr) * (1.0f - wt);
    bin[1] = r0 * NT + t1; cw[1] = (1.0f - wr) * wt;
    bin[2] = r1 * NT + t0; cw[2] = wr * (1.0f - wt);
    bin[3] = r1 * NT + t1; cw[3] = wr * wt;
}

// ---------------------------------------------------------------------------
// Step-0 pair weights (no position update). One wave per (b,n).
// ---------------------------------------------------------------------------
__global__ __launch_bounds__(64) void k_pairs0(const float* __restrict__ p,
                                               const float* __restrict__ car_mask,
                                               float* __restrict__ w4,
                                               int* __restrict__ bin4) {
    int b = blockIdx.x >> 6, n = blockIdx.x & 63;
    int s = threadIdx.x;
    float dx = p[(b * NV + n) * 2 + 0], dy = p[(b * NV + n) * 2 + 1];
    float relx = p[(b * NV + s) * 2 + 0] - dx;
    float rely = p[(b * NV + s) * 2 + 1] - dy;
    float valid, win; int bin[4]; float cw[4];
    pair_geom(relx, rely, car_mask[b * NV + s], valid, win, bin, cw);
    float c = valid;
#pragma unroll
    for (int off = 32; off > 0; off >>= 1) c += __shfl_xor(c, off);
    float bw = valid * win / fmaxf(c, 1.0f);
    int base = (blockIdx.x * NV + s) * 4;
#pragma unroll
    for (int q = 0; q < 4; ++q) { w4[base + q] = bw * cw[q]; bin4[base + q] = bin[q]; }
}

// ---------------------------------------------------------------------------
// advance: writes outputs[t-1], updates p, recomputes vehicle pair weights,
// map encoder (aggregate-then-contract), back-gate and feat update.
// One block of 256 per (b,n).
// ---------------------------------------------------------------------------
__global__ __launch_bounds__(256) void k_advance(int t,
        const float* __restrict__ pprev, float* __restrict__ pcur,
        const float* __restrict__ outD, float* __restrict__ feat,
        const float* __restrict__ w_rho1, const float* __restrict__ WdBack,
        const float* __restrict__ Kmap, const float* __restrict__ map_p,
        const float* __restrict__ map_feat, const float* __restrict__ map_mask,
        const float* __restrict__ car_mask,
        float* __restrict__ w4, int* __restrict__ bin4,
        float* __restrict__ out) {
    __shared__ float s_out0[NV * KR];     // outputD[b,s,0,:]
    __shared__ float s_own[3 * KR];       // outputD[b,n,:,:]
    __shared__ float s_psrc[NV * 2];      // updated source positions
    __shared__ float s_red[256];
    __shared__ float s_G[RTOT * 2];       // map bin accumulator
    __shared__ float s_K[RTOT * KR * KR * 2];   // 24KB K_map
    __shared__ float s_w2[KR * 2];

    int tid = threadIdx.x;
    int b = blockIdx.x >> 6, n = blockIdx.x & 63;

    for (int i = tid; i < NV * KR; i += 256)
        s_out0[i] = outD[(b * NV + (i >> 3)) * 24 + (i & 7)];
    if (tid < 24) s_own[tid] = outD[(b * NV + n) * 24 + tid];
    if (tid < 16) {
        int m = tid >> 1, dd = tid & 1;
        float ang = TWO_PIF * (float)m / (float)KR;
        float sn, cs;
        sincosf(ang, &sn, &cs);
        float w0 = w_rho1[0], wq = w_rho1[1];
        s_w2[tid] = (dd == 0) ? (w0 * cs - wq * sn) : (w0 * sn + wq * cs);
    }
    for (int i = tid; i < RTOT * KR * KR * 2; i += 256) s_K[i] = Kmap[i];
    if (tid < RTOT * 2) s_G[tid] = 0.0f;
    __syncthreads();

    // ---- per-source position update
    if (tid < NV) {
        int s = tid;
        float dx0 = 0.0f, dy0 = 0.0f;
#pragma unroll
        for (int m = 0; m < KR; ++m) {
            float v = s_out0[s * KR + m];
            dx0 = fmaf(v, s_w2[m * 2 + 0], dx0);
            dy0 = fmaf(v, s_w2[m * 2 + 1], dy0);
        }
        s_psrc[s * 2 + 0] = pprev[(b * NV + s) * 2 + 0] + dx0;
        s_psrc[s * 2 + 1] = pprev[(b * NV + s) * 2 + 1] + dy0;
    }
    // ---- outputs[t-1] = reg2rho1(output_{t-1}) (+ p_{t-1} on channel 0)
    if (tid < 6) {
        int c = tid >> 1, dd = tid & 1;
        float acc = 0.0f;
#pragma unroll
        for (int m = 0; m < KR; ++m)
            acc = fmaf(s_own[c * KR + m], s_w2[m * 2 + dd], acc);
        if (c == 0) acc += pprev[(b * NV + n) * 2 + dd];
        out[(((t - 1) * NB + b) * NV + n) * 6 + c * 2 + dd] = acc;
    }
    __syncthreads();
    if (tid < 2) pcur[(b * NV + n) * 2 + tid] = s_psrc[n * 2 + tid];

    float pdx = s_psrc[n * 2 + 0], pdy = s_psrc[n * 2 + 1];

    // ---- vehicle pair weights (wave 0)
    if (tid < NV) {
        int s = tid;
        float relx = s_psrc[s * 2 + 0] - pdx, rely = s_psrc[s * 2 + 1] - pdy;
        float valid, win; int bin[4]; float cw[4];
        pair_geom(relx, rely, car_mask[b * NV + s], valid, win, bin, cw);
        float c = valid;
#pragma unroll
        for (int off = 32; off > 0; off >>= 1) c += __shfl_xor(c, off);
        float bw = valid * win / fmaxf(c, 1.0f);
        int base = (blockIdx.x * NV + s) * 4;
#pragma unroll
        for (int q = 0; q < 4; ++q) { w4[base + q] = bw * cw[q]; bin4[base + q] = bin[q]; }
    }

    // ---- map: count pass
    float lc = 0.0f;
    for (int j = 0; j < NM / 256; ++j) {
        int s = tid + j * 256;
        float relx = map_p[(b * NM + s) * 2 + 0] - pdx;
        float rely = map_p[(b * NM + s) * 2 + 1] - pdy;
        float d = sqrtf(relx * relx + rely * rely + 1e-12f);
        lc += (d < RADIUSF) ? map_mask[b * NM + s] : 0.0f;
    }
    s_red[tid] = lc;
    __syncthreads();
    for (int off = 128; off > 0; off >>= 1) {
        if (tid < off) s_red[tid] += s_red[tid + off];
        __syncthreads();
    }
    float cntm = fmaxf(s_red[0], 1.0f);

    // ---- map: bin aggregation (G_map[rt][d])
    for (int j = 0; j < NM / 256; ++j) {
        int s = tid + j * 256;
        float relx = map_p[(b * NM + s) * 2 + 0] - pdx;
        float rely = map_p[(b * NM + s) * 2 + 1] - pdy;
        float valid, win; int bin[4]; float cw[4];
        pair_geom(relx, rely, map_mask[b * NM + s], valid, win, bin, cw);
        if (valid > 0.0f) {
            float bw = valid * win / cntm;
            float f0 = map_feat[(b * NM + s) * 2 + 0];
            float f1 = map_feat[(b * NM + s) * 2 + 1];
#pragma unroll
            for (int q = 0; q < 4; ++q) {
                float w = bw * cw[q];
                atomicAdd(&s_G[bin[q] * 2 + 0], w * f0);
                atomicAdd(&s_G[bin[q] * 2 + 1], w * f1);
            }
        }
    }
    __syncthreads();

    // ---- map encoder contraction: enc[o,m] = relu(sum_{rt,d} K[rt,o,m,d]*G[rt,d])
    if (tid < 64) {
        int o = tid >> 3, m = tid & 7;
        float acc = 0.0f;
        for (int rt = 0; rt < RTOT; ++rt) {
            acc = fmaf(s_K[rt * 128 + o * 16 + m * 2 + 0], s_G[rt * 2 + 0], acc);
            acc = fmaf(s_K[rt * 128 + o * 16 + m * 2 + 1], s_G[rt * 2 + 1], acc);
        }
        feat[(b * NV + n) * 192 + (16 + o) * 8 + m] = fmaxf(acc, 0.0f);
    }
    // ---- back gate: feat[:16] *= tanh(equilinear(Wd_back, output))
    if (tid < 128) {
        int i = tid >> 3, m = tid & 7;
        float acc = 0.0f;
#pragma unroll
        for (int c = 0; c < 3; ++c)
#pragma unroll
            for (int l = 0; l < KR; ++l)
                acc = fmaf(WdBack[(i * 3 + c) * 8 + l], s_own[c * 8 + ((m - l) & 7)], acc);
        float bk = tanhf(acc);
        int idx = (b * NV + n) * 192 + i * 8 + m;
        feat[idx] = feat[idx] * bk;
    }
}

// ---------------------------------------------------------------------------
// Continuous conv (gather-then-contract) + equilinear (+residual) fused.
// One block of 256 per destination (b,n).
// ---------------------------------------------------------------------------
template<int ICH, int OCH, bool RELU_IN, bool RESID, bool RELU_OUT>
__global__ __launch_bounds__(256) void k_conv(
        const float* __restrict__ inb, const float* __restrict__ Kg,
        const float* __restrict__ Wd, const float* __restrict__ w4,
        const int* __restrict__ bin4, float* __restrict__ outb) {
    constexpr int NC = ICH * KR;                   // 192 or 64
    constexpr int NOUT = OCH * KR;                 // 64 or 24
    constexpr int NQ = (OCH == 8) ? 32 : 64;       // rt*i chunks
    constexpr int SZ = RTOT * ICH;                 // 1152 or 384
    constexpr int CH = SZ / NQ;                    // 36 / 12 / 6
    constexpr int NG = 256 / NC;                   // 1 or 4

    __shared__ float G[RTOT * NC];
    __shared__ float s_w4[NV * 4];
    __shared__ int   s_b4[NV * 4];
    __shared__ float s_in[NC];
    __shared__ float s_part[NQ * NOUT];

    int tid = threadIdx.x;
    int bn = blockIdx.x;
    int b = bn >> 6;

    for (int i = tid; i < RTOT * NC; i += 256) G[i] = 0.0f;
    s_w4[tid] = w4[bn * 256 + tid];
    s_b4[tid] = bin4[bn * 256 + tid];
    if (tid < NC) s_in[tid] = inb[bn * NC + tid];
    __syncthreads();

    // gather: thread owns one feature column, scatters into 4 corner bins
    if (tid < NC * NG) {
        int col = tid % NC, grp = tid / NC;
        for (int s = grp; s < NV; s += NG) {
            float v = inb[(b * NV + s) * NC + col];
            if (RELU_IN) v = fmaxf(v, 0.0f);
#pragma unroll
            for (int q = 0; q < 4; ++q) {
                float w = s_w4[s * 4 + q];
                if (w != 0.0f) atomicAdd(&G[s_b4[s * 4 + q] * NC + col], w * v);
            }
        }
    }
    __syncthreads();

    // contract: thread = (o, chunk of rt*i), keeps all 8 m accumulators
    {
        int q = tid % NQ, o = tid / NQ;
        if (o < OCH) {
            float acc[KR];
#pragma unroll
            for (int m = 0; m < KR; ++m) acc[m] = 0.0f;
            int base = q * CH;
            for (int j = 0; j < CH; ++j) {
                int f = base + j;
                int rt = f / ICH, i = f - rt * ICH;
                const float* Kr = Kg + ((rt * OCH + o) * ICH + i) * KR;
                const float* gr = &G[rt * NC + i * KR];
                float kk[8], gg[8];
                *(float4*)&kk[0] = *(const float4*)&Kr[0];
                *(float4*)&kk[4] = *(const float4*)&Kr[4];
                *(float4*)&gg[0] = *(const float4*)&gr[0];
                *(float4*)&gg[4] = *(const float4*)&gr[4];
#pragma unroll
                for (int l = 0; l < KR; ++l) {
                    float kl = kk[l];
#pragma unroll
                    for (int m = 0; m < KR; ++m)
                        acc[m] = fmaf(kl, gg[(m - l) & 7], acc[m]);
                }
            }
#pragma unroll
            for (int m = 0; m < KR; ++m) s_part[q * NOUT + o * KR + m] = acc[m];
        }
    }
    __syncthreads();

    // reduce + equilinear (+residual)
    if (tid < NOUT) {
        int o = tid / KR, m = tid & 7;
        float tot = 0.0f;
        for (int q = 0; q < NQ; ++q) tot += s_part[q * NOUT + tid];
#pragma unroll
        for (int i = 0; i < ICH; ++i) {
            const float* Wr = Wd + (o * ICH + i) * KR;
#pragma unroll
            for (int l = 0; l < KR; ++l) {
                float v = s_in[i * KR + ((m - l) & 7)];
                if (RELU_IN) v = fmaxf(v, 0.0f);
                tot = fmaf(Wr[l], v, tot);
            }
        }
        if (RESID) tot += s_in[tid];
        if (RELU_OUT) tot = fmaxf(tot, 0.0f);
        outb[bn * NOUT + tid] = tot;
    }
}

// ---------------------------------------------------------------------------
// Final write: outputs[29] = reg2rho1(output_29) (+ p_29 on channel 0)
// ---------------------------------------------------------------------------
__global__ void k_final(const float* __restrict__ outD, const float* __restrict__ pcur,
                        const float* __restrict__ w_rho1, float* __restrict__ out) {
    int idx = blockIdx.x * blockDim.x + threadIdx.x;
    if (idx >= NB * NV * 6) return;
    int bn = idx / 6, r = idx % 6, c = r >> 1, dd = r & 1;
    float w0 = w_rho1[0], wq = w_rho1[1];
    float acc = 0.0f;
#pragma unroll
    for (int m = 0; m < KR; ++m) {
        float ang = TWO_PIF * (float)m / (float)KR;
        float sn, cs;
        sincosf(ang, &sn, &cs);
        float w2 = (dd == 0) ? (w0 * cs - wq * sn) : (w0 * sn + wq * cs);
        acc = fmaf(outD[bn * 24 + c * 8 + m], w2, acc);
    }
    if (c == 0) acc += pcur[bn * 2 + dd];
    out[(29 * NB * NV + bn) * 6 + r] = acc;
}

// ---------------------------------------------------------------------------
extern "C" void kernel_launch(void* const* d_in, const int* in_sizes, int n_in,
                              void* d_out, int out_size, void* d_ws, size_t ws_size,
                              hipStream_t stream) {
    const float* in_p     = (const float*)d_in[0];
    const float* in_feat  = (const float*)d_in[1];
    const float* map_p    = (const float*)d_in[2];
    const float* map_feat = (const float*)d_in[3];
    const float* car_mask = (const float*)d_in[4];
    const float* map_mask = (const float*)d_in[5];
    const float* Kv       = (const float*)d_in[6];
    const float* WdV      = (const float*)d_in[7];
    const float* K1       = (const float*)d_in[8];
    const float* Wd1      = (const float*)d_in[9];
    const float* K2       = (const float*)d_in[10];
    const float* Wd2      = (const float*)d_in[11];
    const float* WdBack   = (const float*)d_in[12];
    const float* w_rho1   = (const float*)d_in[13];
    const float* Kmap     = (const float*)d_in[14];

    float* ws   = (float*)d_ws;
    float* pbuf0 = ws;                 // 1024
    float* pbuf1 = ws + 1024;          // 1024
    float* feat  = ws + 2048;          // 98304  [512][24*8]
    float* out1  = ws + 100352;        // 32768  [512][64]
    float* out2  = ws + 133120;        // 32768  [512][64]
    float* outD  = ws + 165888;        // 12288  [512][24]
    float* w4    = ws + 178176;        // 131072 [512][64][4]
    int*   bin4  = (int*)(ws + 309248);// 131072
    float* out   = (float*)d_out;

    hipMemcpyAsync(pbuf0, in_p, NB * NV * 2 * sizeof(float),
                   hipMemcpyDeviceToDevice, stream);
    hipMemcpyAsync(feat, in_feat, NB * NV * 24 * KR * sizeof(float),
                   hipMemcpyDeviceToDevice, stream);

    k_pairs0<<<NB * NV, 64, 0, stream>>>(pbuf0, car_mask, w4, bin4);

    auto decode = [&]() {
        k_conv<24, 8, false, false, false><<<NB * NV, 256, 0, stream>>>(feat, Kv, WdV, w4, bin4, out1);
        k_conv<8, 8, true, true, false><<<NB * NV, 256, 0, stream>>>(out1, K1, Wd1, w4, bin4, out2);
        k_conv<8, 3, true, false, true><<<NB * NV, 256, 0, stream>>>(out2, K2, Wd2, w4, bin4, outD);
    };

    decode();
    for (int t = 1; t < 30; ++t) {
        float* pprev = (t & 1) ? pbuf0 : pbuf1;
        float* pcur  = (t & 1) ? pbuf1 : pbuf0;
        k_advance<<<NB * NV, 256, 0, stream>>>(t, pprev, pcur, outD, feat,
                                               w_rho1, WdBack, Kmap, map_p, map_feat,
                                               map_mask, car_mask, w4, bin4, out);
        decode();
    }
    k_final<<<12, 256, 0, stream>>>(outD, pbuf1, w_rho1, out);
}

// Round 3
// 7226.873 us; speedup vs baseline: 1.3794x; 1.3794x over previous
//
#include <hip/hip_runtime.h>
#include <math.h>

#define NB 8
#define NV 64
#define NM 1024
#define NR 3
#define NT 16
#define KR 8
#define RTOT 48                 // NR*NT
#define RADIUSF 40.0f
#define TWO_PIF 6.283185307179586f

// ---------------------------------------------------------------------------
// Pair geometry: replicates the reference bilinear polar binning exactly.
// ---------------------------------------------------------------------------
__device__ __forceinline__ void pair_geom(float relx, float rely, float mask,
                                          float& valid, float& win,
                                          int bin[4], float cw[4]) {
    float d = sqrtf(relx * relx + rely * rely + 1e-12f);
    valid = (d < RADIUSF) ? mask : 0.0f;
    float q = d * (1.0f / RADIUSF);
    float w1 = fmaxf(1.0f - q * q, 0.0f);
    win = w1 * w1 * w1;
    float u = fminf(fmaxf(q, 0.0f), 1.0f) * (float)(NR - 1);
    float r0f = floorf(u);
    float wr = u - r0f;
    int r0 = (int)r0f;
    int r1 = min(r0 + 1, NR - 1);
    float a = atan2f(rely, relx) * (1.0f / TWO_PIF);
    a = a - floorf(a);                  // mod 1 -> [0,1)
    float t = a * (float)NT;
    float t0f = floorf(t);
    float wt = t - t0f;
    int t0 = ((int)t0f) & (NT - 1);
    int t1 = (t0 + 1) & (NT - 1);
    bin[0] = r0 * NT + t0; cw[0] = (1.0f - wr) * (1.0f - wt);
    bin[1] = r0 * NT + t1; cw[1] = (1.0f - wr) * wt;
    bin[2] = r1 * NT + t0; cw[2] = wr * (1.0f - wt);
    bin[3] = r1 * NT + t1; cw[3] = wr * wt;
}

// ---------------------------------------------------------------------------
// Step-0 pair weights (no position update). One wave per (b,n).
// ---------------------------------------------------------------------------
__global__ __launch_bounds__(64) void k_pairs0(const float* __restrict__ p,
                                               const float* __restrict__ car_mask,
                                               float* __restrict__ w4,
                                               int* __restrict__ bin4) {
    int b = blockIdx.x >> 6, n = blockIdx.x & 63;
    int s = threadIdx.x;
    float dx = p[(b * NV + n) * 2 + 0], dy = p[(b * NV + n) * 2 + 1];
    float relx = p[(b * NV + s) * 2 + 0] - dx;
    float rely = p[(b * NV + s) * 2 + 1] - dy;
    float valid, win; int bin[4]; float cw[4];
    pair_geom(relx, rely, car_mask[b * NV + s], valid, win, bin, cw);
    float c = valid;
#pragma unroll
    for (int off = 32; off > 0; off >>= 1) c += __shfl_xor(c, off);
    float bw = valid * win / fmaxf(c, 1.0f);
    int base = (blockIdx.x * NV + s) * 4;
#pragma unroll
    for (int q = 0; q < 4; ++q) { w4[base + q] = bw * cw[q]; bin4[base + q] = bin[q]; }
}

// ---------------------------------------------------------------------------
// advance: writes outputs[t-1], updates p, recomputes vehicle pair weights,
// map encoder (aggregate-then-contract), back-gate and feat update.
// One block of 256 per (b,n).  (Verbatim from the R1-passing version.)
// ---------------------------------------------------------------------------
__global__ __launch_bounds__(256) void k_advance(int t,
        const float* __restrict__ pprev, float* __restrict__ pcur,
        const float* __restrict__ outD, float* __restrict__ feat,
        const float* __restrict__ w_rho1, const float* __restrict__ WdBack,
        const float* __restrict__ Kmap, const float* __restrict__ map_p,
        const float* __restrict__ map_feat, const float* __restrict__ map_mask,
        const float* __restrict__ car_mask,
        float* __restrict__ w4, int* __restrict__ bin4,
        float* __restrict__ out) {
    __shared__ float s_out0[NV * KR];     // outputD[b,s,0,:]
    __shared__ float s_own[3 * KR];       // outputD[b,n,:,:]
    __shared__ float s_psrc[NV * 2];      // updated source positions
    __shared__ float s_red[256];
    __shared__ float s_G[RTOT * 2];       // map bin accumulator
    __shared__ float s_K[RTOT * KR * KR * 2];   // 24KB K_map
    __shared__ float s_w2[KR * 2];

    int tid = threadIdx.x;
    int b = blockIdx.x >> 6, n = blockIdx.x & 63;

    for (int i = tid; i < NV * KR; i += 256)
        s_out0[i] = outD[(b * NV + (i >> 3)) * 24 + (i & 7)];
    if (tid < 24) s_own[tid] = outD[(b * NV + n) * 24 + tid];
    if (tid < 16) {
        int m = tid >> 1, dd = tid & 1;
        float ang = TWO_PIF * (float)m / (float)KR;
        float sn, cs;
        sincosf(ang, &sn, &cs);
        float w0 = w_rho1[0], wq = w_rho1[1];
        s_w2[tid] = (dd == 0) ? (w0 * cs - wq * sn) : (w0 * sn + wq * cs);
    }
    for (int i = tid; i < RTOT * KR * KR * 2; i += 256) s_K[i] = Kmap[i];
    if (tid < RTOT * 2) s_G[tid] = 0.0f;
    __syncthreads();

    // ---- per-source position update
    if (tid < NV) {
        int s = tid;
        float dx0 = 0.0f, dy0 = 0.0f;
#pragma unroll
        for (int m = 0; m < KR; ++m) {
            float v = s_out0[s * KR + m];
            dx0 = fmaf(v, s_w2[m * 2 + 0], dx0);
            dy0 = fmaf(v, s_w2[m * 2 + 1], dy0);
        }
        s_psrc[s * 2 + 0] = pprev[(b * NV + s) * 2 + 0] + dx0;
        s_psrc[s * 2 + 1] = pprev[(b * NV + s) * 2 + 1] + dy0;
    }
    // ---- outputs[t-1] = reg2rho1(output_{t-1}) (+ p_{t-1} on channel 0)
    if (tid < 6) {
        int c = tid >> 1, dd = tid & 1;
        float acc = 0.0f;
#pragma unroll
        for (int m = 0; m < KR; ++m)
            acc = fmaf(s_own[c * KR + m], s_w2[m * 2 + dd], acc);
        if (c == 0) acc += pprev[(b * NV + n) * 2 + dd];
        out[(((t - 1) * NB + b) * NV + n) * 6 + c * 2 + dd] = acc;
    }
    __syncthreads();
    if (tid < 2) pcur[(b * NV + n) * 2 + tid] = s_psrc[n * 2 + tid];

    float pdx = s_psrc[n * 2 + 0], pdy = s_psrc[n * 2 + 1];

    // ---- vehicle pair weights (wave 0)
    if (tid < NV) {
        int s = tid;
        float relx = s_psrc[s * 2 + 0] - pdx, rely = s_psrc[s * 2 + 1] - pdy;
        float valid, win; int bin[4]; float cw[4];
        pair_geom(relx, rely, car_mask[b * NV + s], valid, win, bin, cw);
        float c = valid;
#pragma unroll
        for (int off = 32; off > 0; off >>= 1) c += __shfl_xor(c, off);
        float bw = valid * win / fmaxf(c, 1.0f);
        int base = (blockIdx.x * NV + s) * 4;
#pragma unroll
        for (int q = 0; q < 4; ++q) { w4[base + q] = bw * cw[q]; bin4[base + q] = bin[q]; }
    }

    // ---- map: count pass
    float lc = 0.0f;
    for (int j = 0; j < NM / 256; ++j) {
        int s = tid + j * 256;
        float relx = map_p[(b * NM + s) * 2 + 0] - pdx;
        float rely = map_p[(b * NM + s) * 2 + 1] - pdy;
        float d = sqrtf(relx * relx + rely * rely + 1e-12f);
        lc += (d < RADIUSF) ? map_mask[b * NM + s] : 0.0f;
    }
    s_red[tid] = lc;
    __syncthreads();
    for (int off = 128; off > 0; off >>= 1) {
        if (tid < off) s_red[tid] += s_red[tid + off];
        __syncthreads();
    }
    float cntm = fmaxf(s_red[0], 1.0f);

    // ---- map: bin aggregation (G_map[rt][d])
    for (int j = 0; j < NM / 256; ++j) {
        int s = tid + j * 256;
        float relx = map_p[(b * NM + s) * 2 + 0] - pdx;
        float rely = map_p[(b * NM + s) * 2 + 1] - pdy;
        float valid, win; int bin[4]; float cw[4];
        pair_geom(relx, rely, map_mask[b * NM + s], valid, win, bin, cw);
        if (valid > 0.0f) {
            float bw = valid * win / cntm;
            float f0 = map_feat[(b * NM + s) * 2 + 0];
            float f1 = map_feat[(b * NM + s) * 2 + 1];
#pragma unroll
            for (int q = 0; q < 4; ++q) {
                float w = bw * cw[q];
                atomicAdd(&s_G[bin[q] * 2 + 0], w * f0);
                atomicAdd(&s_G[bin[q] * 2 + 1], w * f1);
            }
        }
    }
    __syncthreads();

    // ---- map encoder contraction: enc[o,m] = relu(sum_{rt,d} K[rt,o,m,d]*G[rt,d])
    if (tid < 64) {
        int o = tid >> 3, m = tid & 7;
        float acc = 0.0f;
        for (int rt = 0; rt < RTOT; ++rt) {
            acc = fmaf(s_K[rt * 128 + o * 16 + m * 2 + 0], s_G[rt * 2 + 0], acc);
            acc = fmaf(s_K[rt * 128 + o * 16 + m * 2 + 1], s_G[rt * 2 + 1], acc);
        }
        feat[(b * NV + n) * 192 + (16 + o) * 8 + m] = fmaxf(acc, 0.0f);
    }
    // ---- back gate: feat[:16] *= tanh(equilinear(Wd_back, output))
    if (tid < 128) {
        int i = tid >> 3, m = tid & 7;
        float acc = 0.0f;
#pragma unroll
        for (int c = 0; c < 3; ++c)
#pragma unroll
            for (int l = 0; l < KR; ++l)
                acc = fmaf(WdBack[(i * 3 + c) * 8 + l], s_own[c * 8 + ((m - l) & 7)], acc);
        float bk = tanhf(acc);
        int idx = (b * NV + n) * 192 + i * 8 + m;
        feat[idx] = feat[idx] * bk;
    }
}

// ---------------------------------------------------------------------------
// Continuous conv (gather-then-contract) + equilinear (+residual) fused.
// Gather: R1-verbatim (per-column LDS atomics), G rows padded 8->12 floats.
// Contract: f = j*NQ + q (coalesced K, spread banks), butterfly register
// reduce; equilinear + residual + relu epilogue on lanes q<8.
// ---------------------------------------------------------------------------
template<int ICH, int OCH, bool RELU_IN, bool RESID, bool RELU_OUT>
__global__ __launch_bounds__(256) void k_conv(
        const float* __restrict__ inb, const float* __restrict__ Kg,
        const float* __restrict__ Wd, const float* __restrict__ w4,
        const int* __restrict__ bin4, float* __restrict__ outb) {
    constexpr int NC = ICH * KR;                   // 192 or 64
    constexpr int NOUT = OCH * KR;                 // 64 or 24
    constexpr int NQ = (OCH == 8) ? 32 : 64;
    constexpr int NG = 256 / NC;                   // 1 or 4
    constexpr int GP = 12;                         // padded G row (floats)

    __shared__ __align__(16) float G[RTOT * ICH * GP];
    __shared__ float s_w4[NV * 4];
    __shared__ int   s_b4[NV * 4];
    __shared__ __align__(16) float s_in[NC];

    int tid = threadIdx.x;
    int bn = blockIdx.x;
    int b = bn >> 6;

    for (int i = tid; i < RTOT * ICH * GP; i += 256) G[i] = 0.0f;
    s_w4[tid] = w4[bn * 256 + tid];
    s_b4[tid] = bin4[bn * 256 + tid];
    if (tid < NC) s_in[tid] = inb[bn * NC + tid];
    __syncthreads();

    // gather: thread owns one feature column, scatters into 4 corner bins
    if (tid < NC * NG) {
        int col = tid % NC, grp = tid / NC;
        int ci = col >> 3, cm = col & 7;
        for (int s = grp; s < NV; s += NG) {
            float v = inb[(b * NV + s) * NC + col];
            if (RELU_IN) v = fmaxf(v, 0.0f);
#pragma unroll
            for (int q = 0; q < 4; ++q) {
                float w = s_w4[s * 4 + q];
                if (w != 0.0f)
                    atomicAdd(&G[(s_b4[s * 4 + q] * ICH + ci) * GP + cm], w * v);
            }
        }
    }
    __syncthreads();

    // contract: lane q of o-group handles f = j*NQ + q over all (rt,i)
    const int q = tid & (NQ - 1);
    const int o = tid / NQ;
    if (o < OCH) {
        constexpr int ITERS = (RTOT * ICH) / NQ;   // 36 / 12 / 6 (exact)
        float acc[KR];
#pragma unroll
        for (int m = 0; m < KR; ++m) acc[m] = 0.f;
#pragma unroll 2
        for (int j = 0; j < ITERS; ++j) {
            int f = j * NQ + q;
            int rt = f / ICH, i = f - rt * ICH;
            const float* Kr = Kg + ((rt * OCH + o) * ICH + i) * KR;
            const float* gr = &G[f * GP];
            float kk[8], gg[8];
            *(float4*)&kk[0] = *(const float4*)(Kr);
            *(float4*)&kk[4] = *(const float4*)(Kr + 4);
            *(float4*)&gg[0] = *(const float4*)(gr);
            *(float4*)&gg[4] = *(const float4*)(gr + 4);
#pragma unroll
            for (int l = 0; l < KR; ++l) {
                float kl = kk[l];
#pragma unroll
                for (int m = 0; m < KR; ++m)
                    acc[m] = fmaf(kl, gg[(m - l) & 7], acc[m]);
            }
        }
        // butterfly reduce across the o-group (all lanes end with full sums)
#pragma unroll
        for (int m = 0; m < KR; ++m) {
            acc[m] += __shfl_xor(acc[m], 1);
            acc[m] += __shfl_xor(acc[m], 2);
            acc[m] += __shfl_xor(acc[m], 4);
            acc[m] += __shfl_xor(acc[m], 8);
            acc[m] += __shfl_xor(acc[m], 16);
            if (NQ == 64) acc[m] += __shfl_xor(acc[m], 32);
        }
        if (q < KR) {
            float tot = acc[0];
#pragma unroll
            for (int m = 1; m < KR; ++m) if (q == m) tot = acc[m];
            // equilinear epilogue
#pragma unroll
            for (int i = 0; i < ICH; ++i) {
                const float* Wr = Wd + (o * ICH + i) * KR;
#pragma unroll
                for (int l = 0; l < KR; ++l) {
                    float v = s_in[i * KR + ((q - l) & 7)];
                    if (RELU_IN) v = fmaxf(v, 0.0f);
                    tot = fmaf(Wr[l], v, tot);
                }
            }
            if (RESID) tot += s_in[o * KR + q];
            if (RELU_OUT) tot = fmaxf(tot, 0.f);
            outb[bn * NOUT + o * KR + q] = tot;
        }
    }
}

// ---------------------------------------------------------------------------
// Final write: outputs[29] = reg2rho1(output_29) (+ p_29 on channel 0)
// ---------------------------------------------------------------------------
__global__ void k_final(const float* __restrict__ outD, const float* __restrict__ pcur,
                        const float* __restrict__ w_rho1, float* __restrict__ out) {
    int idx = blockIdx.x * blockDim.x + threadIdx.x;
    if (idx >= NB * NV * 6) return;
    int bn = idx / 6, r = idx % 6, c = r >> 1, dd = r & 1;
    float w0 = w_rho1[0], wq = w_rho1[1];
    float acc = 0.0f;
#pragma unroll
    for (int m = 0; m < KR; ++m) {
        float ang = TWO_PIF * (float)m / (float)KR;
        float sn, cs;
        sincosf(ang, &sn, &cs);
        float w2 = (dd == 0) ? (w0 * cs - wq * sn) : (w0 * sn + wq * cs);
        acc = fmaf(outD[bn * 24 + c * 8 + m], w2, acc);
    }
    if (c == 0) acc += pcur[bn * 2 + dd];
    out[(29 * NB * NV + bn) * 6 + r] = acc;
}

// ---------------------------------------------------------------------------
extern "C" void kernel_launch(void* const* d_in, const int* in_sizes, int n_in,
                              void* d_out, int out_size, void* d_ws, size_t ws_size,
                              hipStream_t stream) {
    const float* in_p     = (const float*)d_in[0];
    const float* in_feat  = (const float*)d_in[1];
    const float* map_p    = (const float*)d_in[2];
    const float* map_feat = (const float*)d_in[3];
    const float* car_mask = (const float*)d_in[4];
    const float* map_mask = (const float*)d_in[5];
    const float* Kv       = (const float*)d_in[6];
    const float* WdV      = (const float*)d_in[7];
    const float* K1       = (const float*)d_in[8];
    const float* Wd1      = (const float*)d_in[9];
    const float* K2       = (const float*)d_in[10];
    const float* Wd2      = (const float*)d_in[11];
    const float* WdBack   = (const float*)d_in[12];
    const float* w_rho1   = (const float*)d_in[13];
    const float* Kmap     = (const float*)d_in[14];

    float* ws   = (float*)d_ws;
    float* pbuf0 = ws;                 // 1024
    float* pbuf1 = ws + 1024;          // 1024
    float* feat  = ws + 2048;          // 98304  [512][24*8]
    float* out1  = ws + 100352;        // 32768  [512][64]
    float* out2  = ws + 133120;        // 32768  [512][64]
    float* outD  = ws + 165888;        // 12288  [512][24]
    float* w4    = ws + 178176;        // 131072 [512][64][4]
    int*   bin4  = (int*)(ws + 309248);// 131072
    float* out   = (float*)d_out;

    hipMemcpyAsync(pbuf0, in_p, NB * NV * 2 * sizeof(float),
                   hipMemcpyDeviceToDevice, stream);
    hipMemcpyAsync(feat, in_feat, NB * NV * 24 * KR * sizeof(float),
                   hipMemcpyDeviceToDevice, stream);

    k_pairs0<<<NB * NV, 64, 0, stream>>>(pbuf0, car_mask, w4, bin4);

    auto decode = [&]() {
        k_conv<24, 8, false, false, false><<<NB * NV, 256, 0, stream>>>(feat, Kv, WdV, w4, bin4, out1);
        k_conv<8, 8, true, true, false><<<NB * NV, 256, 0, stream>>>(out1, K1, Wd1, w4, bin4, out2);
        k_conv<8, 3, true, false, true><<<NB * NV, 256, 0, stream>>>(out2, K2, Wd2, w4, bin4, outD);
    };

    decode();
    for (int t = 1; t < 30; ++t) {
        float* pprev = (t & 1) ? pbuf0 : pbuf1;
        float* pcur  = (t & 1) ? pbuf1 : pbuf0;
        k_advance<<<NB * NV, 256, 0, stream>>>(t, pprev, pcur, outD, feat,
                                               w_rho1, WdBack, Kmap, map_p, map_feat,
                                               map_mask, car_mask, w4, bin4, out);
        decode();
    }
    k_final<<<12, 256, 0, stream>>>(outD, pbuf1, w_rho1, out);
}

// Round 6
// 3591.227 us; speedup vs baseline: 2.7759x; 2.0124x over previous
//
#include <hip/hip_runtime.h>
#include <math.h>

#define NB 8
#define NV 64
#define NM 1024
#define NR 3
#define NT 16
#define KR 8
#define RTOT 48                 // NR*NT
#define RADIUSF 40.0f
#define TWO_PIF 6.283185307179586f

// ---------------------------------------------------------------------------
// Pair geometry: replicates the reference bilinear polar binning exactly.
// ---------------------------------------------------------------------------
__device__ __forceinline__ void pair_geom(float relx, float rely, float mask,
                                          float& valid, float& win,
                                          int bin[4], float cw[4]) {
    float d = sqrtf(relx * relx + rely * rely + 1e-12f);
    valid = (d < RADIUSF) ? mask : 0.0f;
    float q = d * (1.0f / RADIUSF);
    float w1 = fmaxf(1.0f - q * q, 0.0f);
    win = w1 * w1 * w1;
    float u = fminf(fmaxf(q, 0.0f), 1.0f) * (float)(NR - 1);
    float r0f = floorf(u);
    float wr = u - r0f;
    int r0 = (int)r0f;
    int r1 = min(r0 + 1, NR - 1);
    float a = atan2f(rely, relx) * (1.0f / TWO_PIF);
    a = a - floorf(a);                  // mod 1 -> [0,1)
    float t = a * (float)NT;
    float t0f = floorf(t);
    float wt = t - t0f;
    int t0 = ((int)t0f) & (NT - 1);
    int t1 = (t0 + 1) & (NT - 1);
    bin[0] = r0 * NT + t0; cw[0] = (1.0f - wr) * (1.0f - wt);
    bin[1] = r0 * NT + t1; cw[1] = (1.0f - wr) * wt;
    bin[2] = r1 * NT + t0; cw[2] = wr * (1.0f - wt);
    bin[3] = r1 * NT + t1; cw[3] = wr * wt;
}

// ---------------------------------------------------------------------------
// Step-0 pair weights (no position update). One wave per (b,n).  [R3 verbatim]
// ---------------------------------------------------------------------------
__global__ __launch_bounds__(64) void k_pairs0(const float* __restrict__ p,
                                               const float* __restrict__ car_mask,
                                               float* __restrict__ w4,
                                               int* __restrict__ bin4) {
    int b = blockIdx.x >> 6, n = blockIdx.x & 63;
    int s = threadIdx.x;
    float dx = p[(b * NV + n) * 2 + 0], dy = p[(b * NV + n) * 2 + 1];
    float relx = p[(b * NV + s) * 2 + 0] - dx;
    float rely = p[(b * NV + s) * 2 + 1] - dy;
    float valid, win; int bin[4]; float cw[4];
    pair_geom(relx, rely, car_mask[b * NV + s], valid, win, bin, cw);
    float c = valid;
#pragma unroll
    for (int off = 32; off > 0; off >>= 1) c += __shfl_xor(c, off);
    float bw = valid * win / fmaxf(c, 1.0f);
    int base = (blockIdx.x * NV + s) * 4;
#pragma unroll
    for (int q = 0; q < 4; ++q) { w4[base + q] = bw * cw[q]; bin4[base + q] = bin[q]; }
}

// ---------------------------------------------------------------------------
// advance kernel.  [R3 verbatim]
// ---------------------------------------------------------------------------
__global__ __launch_bounds__(256) void k_advance(int t,
        const float* __restrict__ pprev, float* __restrict__ pcur,
        const float* __restrict__ outD, float* __restrict__ feat,
        const float* __restrict__ w_rho1, const float* __restrict__ WdBack,
        const float* __restrict__ Kmap, const float* __restrict__ map_p,
        const float* __restrict__ map_feat, const float* __restrict__ map_mask,
        const float* __restrict__ car_mask,
        float* __restrict__ w4, int* __restrict__ bin4,
        float* __restrict__ out) {
    __shared__ float s_out0[NV * KR];     // outputD[b,s,0,:]
    __shared__ float s_own[3 * KR];       // outputD[b,n,:,:]
    __shared__ float s_psrc[NV * 2];      // updated source positions
    __shared__ float s_red[256];
    __shared__ float s_G[RTOT * 2];       // map bin accumulator
    __shared__ float s_K[RTOT * KR * KR * 2];   // 24KB K_map
    __shared__ float s_w2[KR * 2];

    int tid = threadIdx.x;
    int b = blockIdx.x >> 6, n = blockIdx.x & 63;

    for (int i = tid; i < NV * KR; i += 256)
        s_out0[i] = outD[(b * NV + (i >> 3)) * 24 + (i & 7)];
    if (tid < 24) s_own[tid] = outD[(b * NV + n) * 24 + tid];
    if (tid < 16) {
        int m = tid >> 1, dd = tid & 1;
        float ang = TWO_PIF * (float)m / (float)KR;
        float sn, cs;
        sincosf(ang, &sn, &cs);
        float w0 = w_rho1[0], wq = w_rho1[1];
        s_w2[tid] = (dd == 0) ? (w0 * cs - wq * sn) : (w0 * sn + wq * cs);
    }
    for (int i = tid; i < RTOT * KR * KR * 2; i += 256) s_K[i] = Kmap[i];
    if (tid < RTOT * 2) s_G[tid] = 0.0f;
    __syncthreads();

    // ---- per-source position update
    if (tid < NV) {
        int s = tid;
        float dx0 = 0.0f, dy0 = 0.0f;
#pragma unroll
        for (int m = 0; m < KR; ++m) {
            float v = s_out0[s * KR + m];
            dx0 = fmaf(v, s_w2[m * 2 + 0], dx0);
            dy0 = fmaf(v, s_w2[m * 2 + 1], dy0);
        }
        s_psrc[s * 2 + 0] = pprev[(b * NV + s) * 2 + 0] + dx0;
        s_psrc[s * 2 + 1] = pprev[(b * NV + s) * 2 + 1] + dy0;
    }
    // ---- outputs[t-1] = reg2rho1(output_{t-1}) (+ p_{t-1} on channel 0)
    if (tid < 6) {
        int c = tid >> 1, dd = tid & 1;
        float acc = 0.0f;
#pragma unroll
        for (int m = 0; m < KR; ++m)
            acc = fmaf(s_own[c * KR + m], s_w2[m * 2 + dd], acc);
        if (c == 0) acc += pprev[(b * NV + n) * 2 + dd];
        out[(((t - 1) * NB + b) * NV + n) * 6 + c * 2 + dd] = acc;
    }
    __syncthreads();
    if (tid < 2) pcur[(b * NV + n) * 2 + tid] = s_psrc[n * 2 + tid];

    float pdx = s_psrc[n * 2 + 0], pdy = s_psrc[n * 2 + 1];

    // ---- vehicle pair weights (wave 0)
    if (tid < NV) {
        int s = tid;
        float relx = s_psrc[s * 2 + 0] - pdx, rely = s_psrc[s * 2 + 1] - pdy;
        float valid, win; int bin[4]; float cw[4];
        pair_geom(relx, rely, car_mask[b * NV + s], valid, win, bin, cw);
        float c = valid;
#pragma unroll
        for (int off = 32; off > 0; off >>= 1) c += __shfl_xor(c, off);
        float bw = valid * win / fmaxf(c, 1.0f);
        int base = (blockIdx.x * NV + s) * 4;
#pragma unroll
        for (int q = 0; q < 4; ++q) { w4[base + q] = bw * cw[q]; bin4[base + q] = bin[q]; }
    }

    // ---- map: count pass
    float lc = 0.0f;
    for (int j = 0; j < NM / 256; ++j) {
        int s = tid + j * 256;
        float relx = map_p[(b * NM + s) * 2 + 0] - pdx;
        float rely = map_p[(b * NM + s) * 2 + 1] - pdy;
        float d = sqrtf(relx * relx + rely * rely + 1e-12f);
        lc += (d < RADIUSF) ? map_mask[b * NM + s] : 0.0f;
    }
    s_red[tid] = lc;
    __syncthreads();
    for (int off = 128; off > 0; off >>= 1) {
        if (tid < off) s_red[tid] += s_red[tid + off];
        __syncthreads();
    }
    float cntm = fmaxf(s_red[0], 1.0f);

    // ---- map: bin aggregation (G_map[rt][d])
    for (int j = 0; j < NM / 256; ++j) {
        int s = tid + j * 256;
        float relx = map_p[(b * NM + s) * 2 + 0] - pdx;
        float rely = map_p[(b * NM + s) * 2 + 1] - pdy;
        float valid, win; int bin[4]; float cw[4];
        pair_geom(relx, rely, map_mask[b * NM + s], valid, win, bin, cw);
        if (valid > 0.0f) {
            float bw = valid * win / cntm;
            float f0 = map_feat[(b * NM + s) * 2 + 0];
            float f1 = map_feat[(b * NM + s) * 2 + 1];
#pragma unroll
            for (int q = 0; q < 4; ++q) {
                float w = bw * cw[q];
                atomicAdd(&s_G[bin[q] * 2 + 0], w * f0);
                atomicAdd(&s_G[bin[q] * 2 + 1], w * f1);
            }
        }
    }
    __syncthreads();

    // ---- map encoder contraction
    if (tid < 64) {
        int o = tid >> 3, m = tid & 7;
        float acc = 0.0f;
        for (int rt = 0; rt < RTOT; ++rt) {
            acc = fmaf(s_K[rt * 128 + o * 16 + m * 2 + 0], s_G[rt * 2 + 0], acc);
            acc = fmaf(s_K[rt * 128 + o * 16 + m * 2 + 1], s_G[rt * 2 + 1], acc);
        }
        feat[(b * NV + n) * 192 + (16 + o) * 8 + m] = fmaxf(acc, 0.0f);
    }
    // ---- back gate
    if (tid < 128) {
        int i = tid >> 3, m = tid & 7;
        float acc = 0.0f;
#pragma unroll
        for (int c = 0; c < 3; ++c)
#pragma unroll
            for (int l = 0; l < KR; ++l)
                acc = fmaf(WdBack[(i * 3 + c) * 8 + l], s_own[c * 8 + ((m - l) & 7)], acc);
        float bk = tanhf(acc);
        int idx = (b * NV + n) * 192 + i * 8 + m;
        feat[idx] = feat[idx] * bk;
    }
}

// ---------------------------------------------------------------------------
// FALLBACK PATH: fused conv (gather-then-contract).  [R3 verbatim]
// ---------------------------------------------------------------------------
template<int ICH, int OCH, bool RELU_IN, bool RESID, bool RELU_OUT>
__global__ __launch_bounds__(256) void k_conv(
        const float* __restrict__ inb, const float* __restrict__ Kg,
        const float* __restrict__ Wd, const float* __restrict__ w4,
        const int* __restrict__ bin4, float* __restrict__ outb) {
    constexpr int NC = ICH * KR;                   // 192 or 64
    constexpr int NOUT = OCH * KR;                 // 64 or 24
    constexpr int NQ = (OCH == 8) ? 32 : 64;
    constexpr int NG = 256 / NC;                   // 1 or 4
    constexpr int GP = 12;                         // padded G row (floats)

    __shared__ __align__(16) float G[RTOT * ICH * GP];
    __shared__ float s_w4[NV * 4];
    __shared__ int   s_b4[NV * 4];
    __shared__ __align__(16) float s_in[NC];

    int tid = threadIdx.x;
    int bn = blockIdx.x;
    int b = bn >> 6;

    for (int i = tid; i < RTOT * ICH * GP; i += 256) G[i] = 0.0f;
    s_w4[tid] = w4[bn * 256 + tid];
    s_b4[tid] = bin4[bn * 256 + tid];
    if (tid < NC) s_in[tid] = inb[bn * NC + tid];
    __syncthreads();

    if (tid < NC * NG) {
        int col = tid % NC, grp = tid / NC;
        int ci = col >> 3, cm = col & 7;
        for (int s = grp; s < NV; s += NG) {
            float v = inb[(b * NV + s) * NC + col];
            if (RELU_IN) v = fmaxf(v, 0.0f);
#pragma unroll
            for (int q = 0; q < 4; ++q) {
                float w = s_w4[s * 4 + q];
                if (w != 0.0f)
                    atomicAdd(&G[(s_b4[s * 4 + q] * ICH + ci) * GP + cm], w * v);
            }
        }
    }
    __syncthreads();

    const int q = tid & (NQ - 1);
    const int o = tid / NQ;
    if (o < OCH) {
        constexpr int ITERS = (RTOT * ICH) / NQ;
        float acc[KR];
#pragma unroll
        for (int m = 0; m < KR; ++m) acc[m] = 0.f;
#pragma unroll 2
        for (int j = 0; j < ITERS; ++j) {
            int f = j * NQ + q;
            int rt = f / ICH, i = f - rt * ICH;
            const float* Kr = Kg + ((rt * OCH + o) * ICH + i) * KR;
            const float* gr = &G[f * GP];
            float kk[8], gg[8];
            *(float4*)&kk[0] = *(const float4*)(Kr);
            *(float4*)&kk[4] = *(const float4*)(Kr + 4);
            *(float4*)&gg[0] = *(const float4*)(gr);
            *(float4*)&gg[4] = *(const float4*)(gr + 4);
#pragma unroll
            for (int l = 0; l < KR; ++l) {
                float kl = kk[l];
#pragma unroll
                for (int m = 0; m < KR; ++m)
                    acc[m] = fmaf(kl, gg[(m - l) & 7], acc[m]);
            }
        }
#pragma unroll
        for (int m = 0; m < KR; ++m) {
            acc[m] += __shfl_xor(acc[m], 1);
            acc[m] += __shfl_xor(acc[m], 2);
            acc[m] += __shfl_xor(acc[m], 4);
            acc[m] += __shfl_xor(acc[m], 8);
            acc[m] += __shfl_xor(acc[m], 16);
            if (NQ == 64) acc[m] += __shfl_xor(acc[m], 32);
        }
        if (q < KR) {
            float tot = acc[0];
#pragma unroll
            for (int m = 1; m < KR; ++m) if (q == m) tot = acc[m];
#pragma unroll
            for (int i = 0; i < ICH; ++i) {
                const float* Wr = Wd + (o * ICH + i) * KR;
#pragma unroll
                for (int l = 0; l < KR; ++l) {
                    float v = s_in[i * KR + ((q - l) & 7)];
                    if (RELU_IN) v = fmaxf(v, 0.0f);
                    tot = fmaf(Wr[l], v, tot);
                }
            }
            if (RESID) tot += s_in[o * KR + q];
            if (RELU_OUT) tot = fmaxf(tot, 0.f);
            outb[bn * NOUT + o * KR + q] = tot;
        }
    }
}

// ---------------------------------------------------------------------------
// FAST PATH: one-time K transpose.  [R4 verbatim]
// ---------------------------------------------------------------------------
__global__ __launch_bounds__(256) void k_trans(
        const float* __restrict__ Kv, const float* __restrict__ K1g,
        const float* __restrict__ K2g, float4* __restrict__ KTv,
        float4* __restrict__ KT1, float4* __restrict__ KT2) {
    int idx = blockIdx.x * 256 + threadIdx.x;
    if (idx < 48 * 384) {
        int j = idx / 384, p = idx % 384;
        KTv[idx] = *(const float4*)(Kv + p * 192 + j * 4);
    } else if (idx < 48 * 384 + 16 * 384) {
        int r = idx - 48 * 384;
        int j = r / 384, p = r % 384;
        KT1[r] = *(const float4*)(K1g + p * 64 + j * 4);
    } else if (idx < 48 * 384 + 16 * 384 + 16 * 144) {
        int r = idx - (48 * 384 + 16 * 384);
        int j = r / 144, p = r % 144;
        KT2[r] = *(const float4*)(K2g + p * 64 + j * 4);
    }
}

// ---------------------------------------------------------------------------
// FAST PATH: per-source bin transform H.  [R4 verbatim]
// H[bs, rt, o, m] = sum_{i,l} K[rt,o,i,l] * fin[bs, i, (m-l)&7]
// ---------------------------------------------------------------------------
template<int ICH, int OCH, bool RELU_IN>
__device__ __forceinline__ void h_pair(int bs, int p, const float* s_f,
                                       const float4* __restrict__ KT,
                                       float* __restrict__ H) {
    constexpr int NPAIR = RTOT * OCH;
    constexpr int HS = OCH * KR;
    float acc[KR];
#pragma unroll
    for (int m = 0; m < KR; ++m) acc[m] = 0.f;
    for (int i = 0; i < ICH; ++i) {
        float4 k0 = KT[(2 * i) * NPAIR + p];
        float4 k1 = KT[(2 * i + 1) * NPAIR + p];
        float kk[8] = {k0.x, k0.y, k0.z, k0.w, k1.x, k1.y, k1.z, k1.w};
        float ff[8];
        *(float4*)&ff[0] = *(const float4*)&s_f[i * 8];
        *(float4*)&ff[4] = *(const float4*)&s_f[i * 8 + 4];
#pragma unroll
        for (int l = 0; l < KR; ++l) {
            float kl = kk[l];
#pragma unroll
            for (int m = 0; m < KR; ++m)
                acc[m] = fmaf(kl, ff[(m - l) & 7], acc[m]);
        }
    }
    int rt = p / OCH, o = p - rt * OCH;
    float* hr = H + (size_t)(bs * RTOT + rt) * HS + o * KR;
#pragma unroll
    for (int m = 0; m < KR; ++m) hr[m] = acc[m];
}

template<int ICH, int OCH, bool RELU_IN>
__global__ __launch_bounds__(256) void k_H(const float* __restrict__ inb,
        const float4* __restrict__ KT, float* __restrict__ H) {
    constexpr int NC = ICH * KR;
    constexpr int NPAIR = RTOT * OCH;
    __shared__ __align__(16) float s_f[NC];
    int bs = blockIdx.x, tid = threadIdx.x;
    if (tid < NC) {
        float v = inb[bs * NC + tid];
        if (RELU_IN) v = fmaxf(v, 0.f);
        s_f[tid] = v;
    }
    __syncthreads();
    if (tid < NPAIR)
        h_pair<ICH, OCH, RELU_IN>(bs, tid, s_f, KT, H);
    if (NPAIR > 256 && tid >= 128)
        h_pair<ICH, OCH, RELU_IN>(bs, 128 + tid, s_f, KT, H);
}

// ---------------------------------------------------------------------------
// FAST PATH: per-destination aggregation + equilinear.  [R4 verbatim]
// ---------------------------------------------------------------------------
template<int ICH, int OCH, bool RELU_IN, bool RESID, bool RELU_OUT>
__global__ __launch_bounds__(256) void k_agg(const float* __restrict__ inb,
        const float* __restrict__ H, const float* __restrict__ Wd,
        const float* __restrict__ w4, const int* __restrict__ bin4,
        float* __restrict__ outb) {
    constexpr int NC = ICH * KR;
    constexpr int HS = OCH * KR;
    __shared__ float s_w[256];
    __shared__ int   s_b[256];
    __shared__ float s_in[NC];
    __shared__ float s_part[4 * HS];
    int tid = threadIdx.x, bn = blockIdx.x, b = bn >> 6;
    s_w[tid] = w4[bn * 256 + tid];
    s_b[tid] = bin4[bn * 256 + tid];
    if (tid < NC) s_in[tid] = inb[bn * NC + tid];
    __syncthreads();
    int w = tid >> 6, c = tid & 63;
    if (c < HS) {
        float acc = 0.f;
        for (int j = 0; j < 64; ++j) {
            int idx = w * 64 + j;
            float we = s_w[idx];
            if (we != 0.f) {
                int s = idx >> 2;
                int bin = s_b[idx];
                acc = fmaf(we, H[(size_t)((b * NV + s) * RTOT + bin) * HS + c], acc);
            }
        }
        s_part[w * HS + c] = acc;
    }
    __syncthreads();
    if (tid < HS) {
        float tot = s_part[tid] + s_part[HS + tid] + s_part[2 * HS + tid] + s_part[3 * HS + tid];
        int o = tid / KR, m = tid & 7;
#pragma unroll
        for (int i = 0; i < ICH; ++i) {
            const float* Wr = Wd + (o * ICH + i) * KR;
#pragma unroll
            for (int l = 0; l < KR; ++l) {
                float v = s_in[i * KR + ((m - l) & 7)];
                if (RELU_IN) v = fmaxf(v, 0.f);
                tot = fmaf(Wr[l], v, tot);
            }
        }
        if (RESID) tot += s_in[tid];
        if (RELU_OUT) tot = fmaxf(tot, 0.f);
        outb[bn * HS + tid] = tot;
    }
}

// ---------------------------------------------------------------------------
// Final write: outputs[29]
// ---------------------------------------------------------------------------
__global__ void k_final(const float* __restrict__ outD, const float* __restrict__ pcur,
                        const float* __restrict__ w_rho1, float* __restrict__ out) {
    int idx = blockIdx.x * blockDim.x + threadIdx.x;
    if (idx >= NB * NV * 6) return;
    int bn = idx / 6, r = idx % 6, c = r >> 1, dd = r & 1;
    float w0 = w_rho1[0], wq = w_rho1[1];
    float acc = 0.0f;
#pragma unroll
    for (int m = 0; m < KR; ++m) {
        float ang = TWO_PIF * (float)m / (float)KR;
        float sn, cs;
        sincosf(ang, &sn, &cs);
        float w2 = (dd == 0) ? (w0 * cs - wq * sn) : (w0 * sn + wq * cs);
        acc = fmaf(outD[bn * 24 + c * 8 + m], w2, acc);
    }
    if (c == 0) acc += pcur[bn * 2 + dd];
    out[(29 * NB * NV + bn) * 6 + r] = acc;
}

// ---------------------------------------------------------------------------
extern "C" void kernel_launch(void* const* d_in, const int* in_sizes, int n_in,
                              void* d_out, int out_size, void* d_ws, size_t ws_size,
                              hipStream_t stream) {
    const float* in_p     = (const float*)d_in[0];
    const float* in_feat  = (const float*)d_in[1];
    const float* map_p    = (const float*)d_in[2];
    const float* map_feat = (const float*)d_in[3];
    const float* car_mask = (const float*)d_in[4];
    const float* map_mask = (const float*)d_in[5];
    const float* Kv       = (const float*)d_in[6];
    const float* WdV      = (const float*)d_in[7];
    const float* K1       = (const float*)d_in[8];
    const float* Wd1      = (const float*)d_in[9];
    const float* K2       = (const float*)d_in[10];
    const float* Wd2      = (const float*)d_in[11];
    const float* WdBack   = (const float*)d_in[12];
    const float* w_rho1   = (const float*)d_in[13];
    const float* Kmap     = (const float*)d_in[14];

    // CORRECTED layout: pbuf0/pbuf1 are NB*NV*2 = 1024 floats EACH.
    // (R2/R4/R5 allotted 128 floats -> k_advance's pcur writes clobbered
    //  feat[0..895] and the memcpy clobbered pbuf1: the 3-round failure.)
    float* ws   = (float*)d_ws;
    float* pbuf0 = ws;                       // 1024
    float* pbuf1 = ws + 1024;                // 1024
    float* feat  = ws + 2048;                // 98304  [512][192]
    float* out1  = ws + 100352;              // 32768  [512][64]
    float* out2  = ws + 133120;              // 32768  [512][64]
    float* outD  = ws + 165888;              // 12288  [512][24]
    float* w4    = ws + 178176;              // 131072 [512][256]
    int*   bin4  = (int*)(ws + 309248);      // 131072 ints -> ends 440320 fl
    float4* KTv  = (float4*)(ws + 440320);   // 73728 floats  [48][384] f4
    float4* KT1  = (float4*)(ws + 514048);   // 24576 floats  [16][384] f4
    float4* KT2  = (float4*)(ws + 538624);   // 9216 floats   [16][144] f4
    float* H     = ws + 547840;              // 1572864 floats [512][48][64]
    float* out   = (float*)d_out;

    const size_t need_fast = (size_t)(547840 + 1572864) * sizeof(float); // 8482816 B
    const bool fast = ws_size >= need_fast;

    hipMemcpyAsync(pbuf0, in_p, NB * NV * 2 * sizeof(float),
                   hipMemcpyDeviceToDevice, stream);
    hipMemcpyAsync(feat, in_feat, NB * NV * 24 * KR * sizeof(float),
                   hipMemcpyDeviceToDevice, stream);

    if (fast)
        k_trans<<<105, 256, 0, stream>>>(Kv, K1, K2, KTv, KT1, KT2);
    k_pairs0<<<NB * NV, 64, 0, stream>>>(pbuf0, car_mask, w4, bin4);

    auto decode_fast = [&]() {
        k_H<24, 8, false><<<NB * NV, 256, 0, stream>>>(feat, KTv, H);
        k_agg<24, 8, false, false, false><<<NB * NV, 256, 0, stream>>>(feat, H, WdV, w4, bin4, out1);
        k_H<8, 8, true><<<NB * NV, 256, 0, stream>>>(out1, KT1, H);
        k_agg<8, 8, true, true, false><<<NB * NV, 256, 0, stream>>>(out1, H, Wd1, w4, bin4, out2);
        k_H<8, 3, true><<<NB * NV, 256, 0, stream>>>(out2, KT2, H);
        k_agg<8, 3, true, false, true><<<NB * NV, 256, 0, stream>>>(out2, H, Wd2, w4, bin4, outD);
    };
    auto decode_safe = [&]() {
        k_conv<24, 8, false, false, false><<<NB * NV, 256, 0, stream>>>(feat, Kv, WdV, w4, bin4, out1);
        k_conv<8, 8, true, true, false><<<NB * NV, 256, 0, stream>>>(out1, K1, Wd1, w4, bin4, out2);
        k_conv<8, 3, true, false, true><<<NB * NV, 256, 0, stream>>>(out2, K2, Wd2, w4, bin4, outD);
    };
    auto decode = [&]() { if (fast) decode_fast(); else decode_safe(); };

    decode();
    for (int t = 1; t < 30; ++t) {
        float* pprev = (t & 1) ? pbuf0 : pbuf1;
        float* pcur  = (t & 1) ? pbuf1 : pbuf0;
        k_advance<<<NB * NV, 256, 0, stream>>>(t, pprev, pcur, outD, feat,
                                               w_rho1, WdBack, Kmap, map_p, map_feat,
                                               map_mask, car_mask, w4, bin4, out);
        decode();
    }
    k_final<<<12, 256, 0, stream>>>(outD, pbuf1, w_rho1, out);
}